// Round 1
// 388.627 us; speedup vs baseline: 1.0672x; 1.0672x over previous
//
#include <hip/hip_runtime.h>

#define BATCH 8192
#define DIM 64
#define INV_TEMP 14.2857142857142857f  // 1/0.07
#define EPS_NORM 1e-8f
#define NXB 8           // column blocks  -> grid.x
#define CT_PER_BLOCK 8  // 128-col tiles per block (8*128 = 1024 cols/block)

typedef __attribute__((ext_vector_type(8))) short bf16x8;
typedef __attribute__((ext_vector_type(4))) float f32x4;

__device__ __forceinline__ unsigned short f2bf_rne(float x) {
  unsigned int u = __float_as_uint(x);
  u += 0x7FFFu + ((u >> 16) & 1u);   // round-to-nearest-even
  return (unsigned short)(u >> 16);
}

// ---------------------------------------------------------------------------
// Kernel 1: per-row norms (one wave per row for A and B), write normalized
// bf16 copies. Also zero-init out[0] for the loss atomics.
// ---------------------------------------------------------------------------
__global__ __launch_bounds__(256) void norm_kernel(
    const float* __restrict__ A, const float* __restrict__ Bm,
    unsigned short* __restrict__ An, unsigned short* __restrict__ Bn,
    float* __restrict__ out) {
  int gid  = blockIdx.x * 256 + threadIdx.x;
  int row  = gid >> 6;
  int lane = gid & 63;
  float a = A[row * DIM + lane];
  float b = Bm[row * DIM + lane];
  float sa = a * a, sb = b * b;
#pragma unroll
  for (int m = 32; m; m >>= 1) {   // butterfly: all lanes end with the sum
    sa += __shfl_xor(sa, m);
    sb += __shfl_xor(sb, m);
  }
  float ia = 1.0f / fmaxf(sqrtf(sa), EPS_NORM);
  float ib = 1.0f / fmaxf(sqrtf(sb), EPS_NORM);
  An[row * DIM + lane] = f2bf_rne(a * ia);
  Bn[row * DIM + lane] = f2bf_rne(b * ib);
  if (gid == 0) out[0] = 0.0f;
}

// ---------------------------------------------------------------------------
// Kernel 2: MFMA cos matrix + fused exp / label-masked row sums.
//   block = 256 threads = 4 waves arranged 2x2 over a 128x128 tile.
//   Each block owns 128 rows x 1024 cols (8 col-tiles); A fragments loaded
//   once and reused across the 8 tiles. Regular (cached) stores so L2
//   assembles full lines despite the +4B misalignment of cos_out.
//   No atomics: per-block row partials written to pN/pD.
//   mfma_f32_16x16x32_bf16 C/D: col=lane&15, row=(lane>>4)*4+reg.
// ---------------------------------------------------------------------------
__global__ __launch_bounds__(256) void cos_mfma_kernel(
    const unsigned short* __restrict__ An, const unsigned short* __restrict__ Bn,
    const int* __restrict__ labels,
    float* __restrict__ pN, float* __restrict__ pD,
    float* __restrict__ cos_out) {
  const int tid  = threadIdx.x;
  const int lane = tid & 63;
  const int wave = tid >> 6;
  const int wr = wave >> 1, wc = wave & 1;
  const int m = lane & 15, q = lane >> 4;
  const int row0 = blockIdx.y * 128 + wr * 64;

  // ---- A fragments: loaded once, reused for all 8 col-tiles
  bf16x8 afr[4][2];
#pragma unroll
  for (int t = 0; t < 4; ++t) {
    const unsigned short* ap = An + (size_t)(row0 + t * 16 + m) * DIM + q * 8;
#pragma unroll
    for (int h = 0; h < 2; ++h) afr[t][h] = *(const bf16x8*)(ap + h * 32);
  }

  // ---- own-row labels per (mt, reg)
  int lrw[4][4];
#pragma unroll
  for (int mt = 0; mt < 4; ++mt) {
    int lr = labels[row0 + mt * 16 + m];  // lanes 0..15 hold 16 row labels
#pragma unroll
    for (int i = 0; i < 4; ++i) lrw[mt][i] = __shfl(lr, q * 4 + i);
  }

  float es[4][4], ns[4][4];
#pragma unroll
  for (int mt = 0; mt < 4; ++mt)
#pragma unroll
    for (int i = 0; i < 4; ++i) { es[mt][i] = 0.f; ns[mt][i] = 0.f; }

  // ---- loop over the 8 column tiles owned by this block
  for (int ct = 0; ct < CT_PER_BLOCK; ++ct) {
    const int col0 = (blockIdx.x * CT_PER_BLOCK + ct) * 128 + wc * 64;

    bf16x8 bfr[4][2];
#pragma unroll
    for (int t = 0; t < 4; ++t) {
      const unsigned short* bp = Bn + (size_t)(col0 + t * 16 + m) * DIM + q * 8;
#pragma unroll
      for (int h = 0; h < 2; ++h) bfr[t][h] = *(const bf16x8*)(bp + h * 32);
    }
    int labc[4];
#pragma unroll
    for (int nt = 0; nt < 4; ++nt) labc[nt] = labels[col0 + nt * 16 + m];

#pragma unroll
    for (int mt = 0; mt < 4; ++mt) {
#pragma unroll
      for (int nt = 0; nt < 4; ++nt) {
        f32x4 a = {0.f, 0.f, 0.f, 0.f};
        a = __builtin_amdgcn_mfma_f32_16x16x32_bf16(afr[mt][0], bfr[nt][0], a, 0, 0, 0);
        a = __builtin_amdgcn_mfma_f32_16x16x32_bf16(afr[mt][1], bfr[nt][1], a, 0, 0, 0);
#pragma unroll
        for (int i = 0; i < 4; ++i) {
          float c = a[i];
          size_t row = (size_t)(row0 + mt * 16 + q * 4 + i);
          cos_out[row * BATCH + col0 + nt * 16 + m] = c;  // cached store
          float e = __expf(c * INV_TEMP);
          es[mt][i] += e;
          if (labc[nt] == lrw[mt][i]) ns[mt][i] += e;
        }
      }
    }
  }

  // ---- reduce over the 16 col-lanes within each quad (butterfly)
#pragma unroll
  for (int mt = 0; mt < 4; ++mt)
#pragma unroll
    for (int i = 0; i < 4; ++i) {
      float e = es[mt][i], n = ns[mt][i];
#pragma unroll
      for (int msk = 1; msk < 16; msk <<= 1) {
        e += __shfl_xor(e, msk);
        n += __shfl_xor(n, msk);
      }
      es[mt][i] = e; ns[mt][i] = n;
    }

  // ---- combine the two col-half waves through LDS; write per-block partials
  __shared__ float redN[2][128], redD[2][128];
  if (m == 0) {
#pragma unroll
    for (int mt = 0; mt < 4; ++mt)
#pragma unroll
      for (int i = 0; i < 4; ++i) {
        int r = wr * 64 + mt * 16 + q * 4 + i;
        redN[wc][r] = ns[mt][i];
        redD[wc][r] = es[mt][i];
      }
  }
  __syncthreads();
  if (tid < 128) {
    int row = blockIdx.y * 128 + tid;
    pN[(size_t)blockIdx.x * BATCH + row] = redN[0][tid] + redN[1][tid];
    pD[(size_t)blockIdx.x * BATCH + row] = redD[0][tid] + redD[1][tid];
  }
}

// ---------------------------------------------------------------------------
// Kernel 3: reduce the NXB partials per row, loss = -mean(log(n'/d)).
// 32 blocks x 256 threads = 8192 rows; one atomicAdd per block into out[0]
// (zero-initialized by norm_kernel).
// ---------------------------------------------------------------------------
__global__ __launch_bounds__(256) void loss_kernel(
    const float* __restrict__ pN, const float* __restrict__ pD,
    float* __restrict__ out) {
  int r = blockIdx.x * 256 + threadIdx.x;
  float n = 0.f, d = 0.f;
#pragma unroll
  for (int j = 0; j < NXB; ++j) {
    n += pN[(size_t)j * BATCH + r];
    d += pD[(size_t)j * BATCH + r];
  }
  n = (n == 0.0f) ? (n + 0.01f) : n;
  float s = logf(n / d);
#pragma unroll
  for (int m = 32; m; m >>= 1) s += __shfl_xor(s, m);
  __shared__ float red[4];
  if ((threadIdx.x & 63) == 0) red[threadIdx.x >> 6] = s;
  __syncthreads();
  if (threadIdx.x == 0) {
    float t = red[0] + red[1] + red[2] + red[3];
    atomicAdd(out, -t / (float)BATCH);
  }
}

// ---------------------------------------------------------------------------
extern "C" void kernel_launch(void* const* d_in, const int* in_sizes, int n_in,
                              void* d_out, int out_size, void* d_ws, size_t ws_size,
                              hipStream_t stream) {
  const int*   labels = (const int*)d_in[0];
  const float* A      = (const float*)d_in[1];
  const float* Bf     = (const float*)d_in[2];
  float* out = (float*)d_out;  // out[0]=loss, out[1..]=cos_score row-major

  unsigned short* An = (unsigned short*)d_ws;                 // 1 MB
  unsigned short* Bn = An + BATCH * DIM;                      // 1 MB
  float* pN = (float*)(Bn + BATCH * DIM);                     // NXB*32 KB = 256 KB
  float* pD = pN + (size_t)NXB * BATCH;                       // 256 KB

  hipLaunchKernelGGL(norm_kernel, dim3(BATCH * 64 / 256), dim3(256), 0, stream,
                     A, Bf, An, Bn, out);
  hipLaunchKernelGGL(cos_mfma_kernel, dim3(NXB, BATCH / 128), dim3(256),
                     0, stream, An, Bn, labels, pN, pD, out + 1);
  hipLaunchKernelGGL(loss_kernel, dim3(BATCH / 256), dim3(256), 0, stream,
                     pN, pD, out);
}

// Round 5
// 352.828 us; speedup vs baseline: 1.1755x; 1.1015x over previous
//
#include <hip/hip_runtime.h>

#define BATCH 8192
#define DIM 64
#define INV_TEMP 14.2857142857142857f  // 1/0.07
#define EPS_NORM 1e-8f
#define NXB 32          // column blocks  -> grid.x
#define CT_PER_BLOCK 2  // 128-col tiles per block (2*128 = 256 cols/block)

typedef __attribute__((ext_vector_type(8))) short bf16x8;
typedef __attribute__((ext_vector_type(4))) float f32x4;

__device__ __forceinline__ unsigned short f2bf_rne(float x) {
  unsigned int u = __float_as_uint(x);
  u += 0x7FFFu + ((u >> 16) & 1u);   // round-to-nearest-even
  return (unsigned short)(u >> 16);
}

// ---------------------------------------------------------------------------
// Kernel 1: per-row norms (one wave per row for A and B), write normalized
// bf16 copies. Also zero-init out[0] for the loss atomics.
// ---------------------------------------------------------------------------
__global__ __launch_bounds__(256) void norm_kernel(
    const float* __restrict__ A, const float* __restrict__ Bm,
    unsigned short* __restrict__ An, unsigned short* __restrict__ Bn,
    float* __restrict__ out) {
  int gid  = blockIdx.x * 256 + threadIdx.x;
  int row  = gid >> 6;
  int lane = gid & 63;
  float a = A[row * DIM + lane];
  float b = Bm[row * DIM + lane];
  float sa = a * a, sb = b * b;
#pragma unroll
  for (int m = 32; m; m >>= 1) {   // butterfly: all lanes end with the sum
    sa += __shfl_xor(sa, m);
    sb += __shfl_xor(sb, m);
  }
  float ia = 1.0f / fmaxf(sqrtf(sa), EPS_NORM);
  float ib = 1.0f / fmaxf(sqrtf(sb), EPS_NORM);
  An[row * DIM + lane] = f2bf_rne(a * ia);
  Bn[row * DIM + lane] = f2bf_rne(b * ib);
  if (gid == 0) out[0] = 0.0f;
}

// ---------------------------------------------------------------------------
// Kernel 2: MFMA cos matrix + fused exp / label-masked row sums.
//   block = 256 threads = 4 waves arranged 2x2 over a 128x128 tile.
//   Each block owns 128 rows x 256 cols (2 col-tiles); 2048 blocks give
//   ~6 resident blocks/CU for store concurrency. No atomics.
//
//   cos_out is +4B misaligned, so every 128B line straddles a 256-col block
//   boundary: line covering cols [256k-1, 256k+30] has TWO writer blocks.
//   Cached stores to such lines race via non-coherent per-XCD L2 dirty
//   copies (round-3 post-timing divergence). Fix: stores with
//   (c mod 256) in {255} U [0,30] go nontemporal (byte-masked at memory,
//   never cached-dirty); all other lines are single-writer, fully
//   assembled in L2 and written back as full lines.
//   mfma_f32_16x16x32_bf16 C/D: col=lane&15, row=(lane>>4)*4+reg.
// ---------------------------------------------------------------------------
__global__ __launch_bounds__(256) void cos_mfma_kernel(
    const unsigned short* __restrict__ An, const unsigned short* __restrict__ Bn,
    const int* __restrict__ labels,
    float* __restrict__ pN, float* __restrict__ pD,
    float* __restrict__ cos_out) {
  const int tid  = threadIdx.x;
  const int lane = tid & 63;
  const int wave = tid >> 6;
  const int wr = wave >> 1, wc = wave & 1;
  const int m = lane & 15, q = lane >> 4;
  const int row0 = blockIdx.y * 128 + wr * 64;

  // ---- A fragments: loaded once, reused for both col-tiles
  bf16x8 afr[4][2];
#pragma unroll
  for (int t = 0; t < 4; ++t) {
    const unsigned short* ap = An + (size_t)(row0 + t * 16 + m) * DIM + q * 8;
#pragma unroll
    for (int h = 0; h < 2; ++h) afr[t][h] = *(const bf16x8*)(ap + h * 32);
  }

  // ---- own-row labels per (mt, reg)
  int lrw[4][4];
#pragma unroll
  for (int mt = 0; mt < 4; ++mt) {
    int lr = labels[row0 + mt * 16 + m];  // lanes 0..15 hold 16 row labels
#pragma unroll
    for (int i = 0; i < 4; ++i) lrw[mt][i] = __shfl(lr, q * 4 + i);
  }

  float es[4][4], ns[4][4];
#pragma unroll
  for (int mt = 0; mt < 4; ++mt)
#pragma unroll
    for (int i = 0; i < 4; ++i) { es[mt][i] = 0.f; ns[mt][i] = 0.f; }

  // ---- loop over the column tiles owned by this block
#pragma unroll
  for (int ct = 0; ct < CT_PER_BLOCK; ++ct) {
    const int col0 = (blockIdx.x * CT_PER_BLOCK + ct) * 128 + wc * 64;

    bf16x8 bfr[4][2];
#pragma unroll
    for (int t = 0; t < 4; ++t) {
      const unsigned short* bp = Bn + (size_t)(col0 + t * 16 + m) * DIM + q * 8;
#pragma unroll
      for (int h = 0; h < 2; ++h) bfr[t][h] = *(const bf16x8*)(bp + h * 32);
    }
    int labc[4];
#pragma unroll
    for (int nt = 0; nt < 4; ++nt) labc[nt] = labels[col0 + nt * 16 + m];

#pragma unroll
    for (int mt = 0; mt < 4; ++mt) {
#pragma unroll
      for (int nt = 0; nt < 4; ++nt) {
        f32x4 a = {0.f, 0.f, 0.f, 0.f};
        a = __builtin_amdgcn_mfma_f32_16x16x32_bf16(afr[mt][0], bfr[nt][0], a, 0, 0, 0);
        a = __builtin_amdgcn_mfma_f32_16x16x32_bf16(afr[mt][1], bfr[nt][1], a, 0, 0, 0);
        // col within this block's 256-col span (blockIdx.x*256 drops mod 256)
        const int cmod = ct * 128 + wc * 64 + nt * 16 + m;
        const bool edge = (cmod == 255) || (cmod <= 30);  // shared-line cols
#pragma unroll
        for (int i = 0; i < 4; ++i) {
          float c = a[i];
          size_t row = (size_t)(row0 + mt * 16 + q * 4 + i);
          float* p = cos_out + row * BATCH + col0 + nt * 16 + m;
          if (edge) __builtin_nontemporal_store(c, p);
          else      *p = c;
          float e = __expf(c * INV_TEMP);
          es[mt][i] += e;
          if (labc[nt] == lrw[mt][i]) ns[mt][i] += e;
        }
      }
    }
  }

  // ---- reduce over the 16 col-lanes within each quad (butterfly)
#pragma unroll
  for (int mt = 0; mt < 4; ++mt)
#pragma unroll
    for (int i = 0; i < 4; ++i) {
      float e = es[mt][i], n = ns[mt][i];
#pragma unroll
      for (int msk = 1; msk < 16; msk <<= 1) {
        e += __shfl_xor(e, msk);
        n += __shfl_xor(n, msk);
      }
      es[mt][i] = e; ns[mt][i] = n;
    }

  // ---- combine the two col-half waves through LDS; write per-block partials
  __shared__ float redN[2][128], redD[2][128];
  if (m == 0) {
#pragma unroll
    for (int mt = 0; mt < 4; ++mt)
#pragma unroll
      for (int i = 0; i < 4; ++i) {
        int r = wr * 64 + mt * 16 + q * 4 + i;
        redN[wc][r] = ns[mt][i];
        redD[wc][r] = es[mt][i];
      }
  }
  __syncthreads();
  if (tid < 128) {
    int row = blockIdx.y * 128 + tid;
    pN[(size_t)blockIdx.x * BATCH + row] = redN[0][tid] + redN[1][tid];
    pD[(size_t)blockIdx.x * BATCH + row] = redD[0][tid] + redD[1][tid];
  }
}

// ---------------------------------------------------------------------------
// Kernel 3: reduce the NXB partials per row, loss = -mean(log(n'/d)).
// 32 blocks x 256 threads = 8192 rows; one atomicAdd per block into out[0]
// (zero-initialized by norm_kernel).
// ---------------------------------------------------------------------------
__global__ __launch_bounds__(256) void loss_kernel(
    const float* __restrict__ pN, const float* __restrict__ pD,
    float* __restrict__ out) {
  int r = blockIdx.x * 256 + threadIdx.x;
  float n = 0.f, d = 0.f;
#pragma unroll
  for (int j = 0; j < NXB; ++j) {
    n += pN[(size_t)j * BATCH + r];
    d += pD[(size_t)j * BATCH + r];
  }
  n = (n == 0.0f) ? (n + 0.01f) : n;
  float s = logf(n / d);
#pragma unroll
  for (int m = 32; m; m >>= 1) s += __shfl_xor(s, m);
  __shared__ float red[4];
  if ((threadIdx.x & 63) == 0) red[threadIdx.x >> 6] = s;
  __syncthreads();
  if (threadIdx.x == 0) {
    float t = red[0] + red[1] + red[2] + red[3];
    atomicAdd(out, -t / (float)BATCH);
  }
}

// ---------------------------------------------------------------------------
extern "C" void kernel_launch(void* const* d_in, const int* in_sizes, int n_in,
                              void* d_out, int out_size, void* d_ws, size_t ws_size,
                              hipStream_t stream) {
  const int*   labels = (const int*)d_in[0];
  const float* A      = (const float*)d_in[1];
  const float* Bf     = (const float*)d_in[2];
  float* out = (float*)d_out;  // out[0]=loss, out[1..]=cos_score row-major

  unsigned short* An = (unsigned short*)d_ws;                 // 1 MB
  unsigned short* Bn = An + BATCH * DIM;                      // 1 MB
  float* pN = (float*)(Bn + BATCH * DIM);                     // NXB*32 KB = 1 MB
  float* pD = pN + (size_t)NXB * BATCH;                       // 1 MB

  hipLaunchKernelGGL(norm_kernel, dim3(BATCH * 64 / 256), dim3(256), 0, stream,
                     A, Bf, An, Bn, out);
  hipLaunchKernelGGL(cos_mfma_kernel, dim3(NXB, BATCH / 128), dim3(256),
                     0, stream, An, Bn, labels, pN, pD, out + 1);
  hipLaunchKernelGGL(loss_kernel, dim3(BATCH / 256), dim3(256), 0, stream,
                     pN, pD, out);
}

// Round 6
// 349.591 us; speedup vs baseline: 1.1864x; 1.0093x over previous
//
#include <hip/hip_runtime.h>

#define BATCH 8192
#define DIM 64
#define INV_TEMP 14.2857142857142857f  // 1/0.07
#define EPS_NORM 1e-8f
#define NXB 32          // column blocks  -> grid.x
#define CT_PER_BLOCK 2  // 128-col tiles per block (2*128 = 256 cols/block)

typedef __attribute__((ext_vector_type(8))) short bf16x8;
typedef __attribute__((ext_vector_type(4))) float f32x4;

// 16B vector store at 4B alignment (cos_out is +4B off line alignment).
struct __attribute__((packed, aligned(4))) f32x4_u { f32x4 v; };

__device__ __forceinline__ unsigned short f2bf_rne(float x) {
  unsigned int u = __float_as_uint(x);
  u += 0x7FFFu + ((u >> 16) & 1u);   // round-to-nearest-even
  return (unsigned short)(u >> 16);
}

// ---------------------------------------------------------------------------
// Kernel 1: per-row norms (one wave per row for A and B), write normalized
// bf16 copies. Also zero-init out[0] for the loss atomics.
// ---------------------------------------------------------------------------
__global__ __launch_bounds__(256) void norm_kernel(
    const float* __restrict__ A, const float* __restrict__ Bm,
    unsigned short* __restrict__ An, unsigned short* __restrict__ Bn,
    float* __restrict__ out) {
  int gid  = blockIdx.x * 256 + threadIdx.x;
  int row  = gid >> 6;
  int lane = gid & 63;
  float a = A[row * DIM + lane];
  float b = Bm[row * DIM + lane];
  float sa = a * a, sb = b * b;
#pragma unroll
  for (int m = 32; m; m >>= 1) {   // butterfly: all lanes end with the sum
    sa += __shfl_xor(sa, m);
    sb += __shfl_xor(sb, m);
  }
  float ia = 1.0f / fmaxf(sqrtf(sa), EPS_NORM);
  float ib = 1.0f / fmaxf(sqrtf(sb), EPS_NORM);
  An[row * DIM + lane] = f2bf_rne(a * ia);
  Bn[row * DIM + lane] = f2bf_rne(b * ib);
  if (gid == 0) out[0] = 0.0f;
}

// ---------------------------------------------------------------------------
// Kernel 2: MFMA cos matrix + fused exp / label-masked row sums.
//   block = 256 threads = 4 waves arranged 2x2 over a 128x128 tile; each
//   block owns 128 rows x 256 cols (2 col-tiles), grid 32x64 = 2048 blocks.
//
//   SWAPPED-OPERAND MFMA: mfma(bfr, afr) puts S[row][col] at
//   row = lane&15 (m), col = q*4 + reg  ->  each lane's f32x4 accumulator is
//   4 CONSECUTIVE columns of one row == a global_store_dwordx4 payload.
//   4x fewer store instructions, ~2x fewer line-transactions vs dword stores.
//
//   cos_out is +4B misaligned: the 128B line covering cols [256k-1,256k+30]
//   has two writer blocks -> cross-XCD dirty-line race if cached (round 3).
//   Line-clean policy: cols {0..30, 255} mod 256 stored NONTEMPORAL by both
//   sharers, everything else cached (full-line L2 assembly). Edge store
//   instructions (cmod<=28 or ==252) scalarize to keep per-line purity
//   (e.g. col 31 cached even though it sits in an edge dwordx4).
//   mfma_f32_16x16x32_bf16 C/D: col=lane&15, row=(lane>>4)*4+reg.
// ---------------------------------------------------------------------------
__global__ __launch_bounds__(256) void cos_mfma_kernel(
    const unsigned short* __restrict__ An, const unsigned short* __restrict__ Bn,
    const int* __restrict__ labels,
    float* __restrict__ pN, float* __restrict__ pD,
    float* __restrict__ cos_out) {
  const int tid  = threadIdx.x;
  const int lane = tid & 63;
  const int wave = tid >> 6;
  const int wr = wave >> 1, wc = wave & 1;
  const int m = lane & 15, q = lane >> 4;
  const int row0 = blockIdx.y * 128 + wr * 64;

  // ---- A fragments: loaded once, reused for both col-tiles
  bf16x8 afr[4][2];
#pragma unroll
  for (int t = 0; t < 4; ++t) {
    const unsigned short* ap = An + (size_t)(row0 + t * 16 + m) * DIM + q * 8;
#pragma unroll
    for (int h = 0; h < 2; ++h) afr[t][h] = *(const bf16x8*)(ap + h * 32);
  }

  // ---- own-row labels: lane's row for tile mt is row0 + mt*16 + m
  int lrw[4];
#pragma unroll
  for (int mt = 0; mt < 4; ++mt) lrw[mt] = labels[row0 + mt * 16 + m];

  float es[4], ns[4];
#pragma unroll
  for (int mt = 0; mt < 4; ++mt) { es[mt] = 0.f; ns[mt] = 0.f; }

  // ---- loop over the column tiles owned by this block
#pragma unroll
  for (int ct = 0; ct < CT_PER_BLOCK; ++ct) {
    const int col0 = (blockIdx.x * CT_PER_BLOCK + ct) * 128 + wc * 64;

    bf16x8 bfr[4][2];
#pragma unroll
    for (int t = 0; t < 4; ++t) {
      const unsigned short* bp = Bn + (size_t)(col0 + t * 16 + m) * DIM + q * 8;
#pragma unroll
      for (int h = 0; h < 2; ++h) bfr[t][h] = *(const bf16x8*)(bp + h * 32);
    }
    // col labels: lane needs labels of cols col0 + nt*16 + q*4 .. +3 (16B int4)
    int4 labc[4];
#pragma unroll
    for (int nt = 0; nt < 4; ++nt)
      labc[nt] = *(const int4*)&labels[col0 + nt * 16 + q * 4];

#pragma unroll
    for (int mt = 0; mt < 4; ++mt) {
#pragma unroll
      for (int nt = 0; nt < 4; ++nt) {
        f32x4 a = {0.f, 0.f, 0.f, 0.f};
        a = __builtin_amdgcn_mfma_f32_16x16x32_bf16(bfr[nt][0], afr[mt][0], a, 0, 0, 0);
        a = __builtin_amdgcn_mfma_f32_16x16x32_bf16(bfr[nt][1], afr[mt][1], a, 0, 0, 0);
        // lane holds S[row0+mt*16+m][col0+nt*16+q*4+r], r = 0..3
        const int cmod = ct * 128 + wc * 64 + nt * 16 + q * 4;  // col mod 256
        float* p = cos_out + (size_t)(row0 + mt * 16 + m) * BATCH
                           + (col0 + nt * 16 + q * 4);
        if ((cmod <= 28) || (cmod == 252)) {
          // edge: scalarize with per-column policy to keep lines policy-pure
#pragma unroll
          for (int r = 0; r < 4; ++r) {
            int colm = cmod + r;
            if (colm <= 30 || colm == 255) __builtin_nontemporal_store(a[r], p + r);
            else                           p[r] = a[r];
          }
        } else {
          ((f32x4_u*)p)->v = a;   // cached dwordx4 (4B-aligned)
        }
        float e0 = __expf(a[0] * INV_TEMP);
        float e1 = __expf(a[1] * INV_TEMP);
        float e2 = __expf(a[2] * INV_TEMP);
        float e3 = __expf(a[3] * INV_TEMP);
        es[mt] += (e0 + e1) + (e2 + e3);
        float nacc = 0.f;
        if (labc[nt].x == lrw[mt]) nacc += e0;
        if (labc[nt].y == lrw[mt]) nacc += e1;
        if (labc[nt].z == lrw[mt]) nacc += e2;
        if (labc[nt].w == lrw[mt]) nacc += e3;
        ns[mt] += nacc;
      }
    }
  }

  // ---- reduce over the 4 q-lanes (lane bits 4,5) sharing each row m
#pragma unroll
  for (int mt = 0; mt < 4; ++mt) {
    float e = es[mt], n = ns[mt];
    e += __shfl_xor(e, 16); n += __shfl_xor(n, 16);
    e += __shfl_xor(e, 32); n += __shfl_xor(n, 32);
    es[mt] = e; ns[mt] = n;
  }

  // ---- combine the two col-half waves through LDS; write per-block partials
  __shared__ float redN[2][128], redD[2][128];
  if (q == 0) {
#pragma unroll
    for (int mt = 0; mt < 4; ++mt) {
      int r = wr * 64 + mt * 16 + m;
      redN[wc][r] = ns[mt];
      redD[wc][r] = es[mt];
    }
  }
  __syncthreads();
  if (tid < 128) {
    int row = blockIdx.y * 128 + tid;
    pN[(size_t)blockIdx.x * BATCH + row] = redN[0][tid] + redN[1][tid];
    pD[(size_t)blockIdx.x * BATCH + row] = redD[0][tid] + redD[1][tid];
  }
}

// ---------------------------------------------------------------------------
// Kernel 3: reduce the NXB partials per row, loss = -mean(log(n'/d)).
// 32 blocks x 256 threads = 8192 rows; one atomicAdd per block into out[0]
// (zero-initialized by norm_kernel).
// ---------------------------------------------------------------------------
__global__ __launch_bounds__(256) void loss_kernel(
    const float* __restrict__ pN, const float* __restrict__ pD,
    float* __restrict__ out) {
  int r = blockIdx.x * 256 + threadIdx.x;
  float n = 0.f, d = 0.f;
#pragma unroll
  for (int j = 0; j < NXB; ++j) {
    n += pN[(size_t)j * BATCH + r];
    d += pD[(size_t)j * BATCH + r];
  }
  n = (n == 0.0f) ? (n + 0.01f) : n;
  float s = logf(n / d);
#pragma unroll
  for (int m = 32; m; m >>= 1) s += __shfl_xor(s, m);
  __shared__ float red[4];
  if ((threadIdx.x & 63) == 0) red[threadIdx.x >> 6] = s;
  __syncthreads();
  if (threadIdx.x == 0) {
    float t = red[0] + red[1] + red[2] + red[3];
    atomicAdd(out, -t / (float)BATCH);
  }
}

// ---------------------------------------------------------------------------
extern "C" void kernel_launch(void* const* d_in, const int* in_sizes, int n_in,
                              void* d_out, int out_size, void* d_ws, size_t ws_size,
                              hipStream_t stream) {
  const int*   labels = (const int*)d_in[0];
  const float* A      = (const float*)d_in[1];
  const float* Bf     = (const float*)d_in[2];
  float* out = (float*)d_out;  // out[0]=loss, out[1..]=cos_score row-major

  unsigned short* An = (unsigned short*)d_ws;                 // 1 MB
  unsigned short* Bn = An + BATCH * DIM;                      // 1 MB
  float* pN = (float*)(Bn + BATCH * DIM);                     // NXB*32 KB = 1 MB
  float* pD = pN + (size_t)NXB * BATCH;                       // 1 MB

  hipLaunchKernelGGL(norm_kernel, dim3(BATCH * 64 / 256), dim3(256), 0, stream,
                     A, Bf, An, Bn, out);
  hipLaunchKernelGGL(cos_mfma_kernel, dim3(NXB, BATCH / 128), dim3(256),
                     0, stream, An, Bn, labels, pN, pD, out + 1);
  hipLaunchKernelGGL(loss_kernel, dim3(BATCH / 256), dim3(256), 0, stream,
                     pN, pD, out);
}